// Round 1
// baseline (834.284 us; speedup 1.0000x reference)
//
#include <hip/hip_runtime.h>

#define BLOCK 256
#define TILE  1024              // records per block-iteration
#define NBLK  2048              // 8 blocks/CU * 256 CU, exactly resident, %8==0

typedef float f4 __attribute__((ext_vector_type(4)));
typedef int   i4 __attribute__((ext_vector_type(4)));

// out[b,i,j,h] = W[h, rel_pos[b,i,j]] — float32 gather, 12 floats (3 x float4) per record.
// v4: persistent grid-stride. 2048 blocks, each owns n_tiles/2048 tiles of 1024 records.
//   - W-table (64 recs x 12 f32 = 3 KB) staged to LDS ONCE per block (was: per 256 recs).
//   - Indices staged as int4 per thread (global dwordx4 -> ds_write_b128, conflict-free).
//   - Gather phase: chunk j = t + 256k (k=0..11), p=j/3 (magic mul), s=j%3;
//     ds_read_b128 from tab[cls[p]*12 + 4s], coalesced nontemporal dwordx4 store.
__global__ __launch_bounds__(BLOCK) void gather12_v4(
    const int* __restrict__ rel_pos,
    const float* __restrict__ W,        // [12][64] float32
    f4* __restrict__ out,
    unsigned int n_rec,
    unsigned int n_tiles)
{
    __shared__ float tab[64 * 12];      // tab[c*12+h] = W[h][c]; each chunk 16B-aligned
    __shared__ int cls[TILE];

    const int t = threadIdx.x;

    // ---- table: once per block ----
#pragma unroll
    for (int i = 0; i < 3; ++i) {
        int idx = t + i * BLOCK;        // 0..767
        int h = idx >> 6;               // 0..11
        int c = idx & 63;               // 0..63
        tab[c * 12 + h] = W[idx];
    }

    const unsigned long long total_chunks = (unsigned long long)n_rec * 3ull;

    for (unsigned int tile = blockIdx.x; tile < n_tiles; tile += gridDim.x) {
        const unsigned int recBase = tile * TILE;

        // ---- stage 1024 indices: int4 per thread ----
        {
            unsigned int r = recBase + (unsigned int)t * 4u;
            if (r + 3u < n_rec) {
                *(i4*)&cls[t * 4] = *(const i4*)&rel_pos[r];
            } else {
#pragma unroll
                for (int e = 0; e < 4; ++e)
                    cls[t * 4 + e] = (r + (unsigned)e < n_rec) ? rel_pos[r + e] : 0;
            }
        }
        __syncthreads();

        // ---- gather + coalesced store: 3072 chunks, 12 per thread ----
        const unsigned long long chunkBase = (unsigned long long)recBase * 3ull;
#pragma unroll
        for (int k = 0; k < 12; ++k) {
            unsigned int j = (unsigned int)t + BLOCK * (unsigned int)k;  // 0..3071
            unsigned int p = j / 3u;                    // const divisor -> magic mul
            unsigned int s = j - p * 3u;                // 0,1,2
            unsigned int c = (unsigned int)cls[p];      // LDS, 3-way broadcast (free)
            f4 v = *(const f4*)(tab + c * 12u + 4u * s); // ds_read_b128
            if (chunkBase + j < total_chunks)
                __builtin_nontemporal_store(v, &out[chunkBase + j]);
        }
        __syncthreads();                 // cls reused next iteration
    }
}

extern "C" void kernel_launch(void* const* d_in, const int* in_sizes, int n_in,
                              void* d_out, int out_size, void* d_ws, size_t ws_size,
                              hipStream_t stream)
{
    const int* rel_pos = (const int*)d_in[0];
    // d_in[1] = hidden_states: unused (reference only uses its dtype)
    const float* W = (const float*)d_in[2];

    const unsigned int n_rec = (unsigned int)in_sizes[0];          // 4*2048*2048
    const unsigned int n_tiles = (n_rec + TILE - 1) / TILE;        // 16384
    const unsigned int blocks = (n_tiles < NBLK) ? n_tiles : NBLK; // 2048

    gather12_v4<<<blocks, BLOCK, 0, stream>>>(rel_pos, W, (f4*)d_out, n_rec, n_tiles);
}

// Round 2
// 825.967 us; speedup vs baseline: 1.0101x; 1.0101x over previous
//
#include <hip/hip_runtime.h>

#define BLOCK 256
#define TILE  1024              // records per block-iteration
#define NBLK  2048              // 8 blocks/CU * 256 CU, exactly resident, %8==0

typedef float f4 __attribute__((ext_vector_type(4)));
typedef int   i4 __attribute__((ext_vector_type(4)));

// out[b,i,j,h] = W[h, rel_pos[b,i,j]] — float32 gather, 12 floats (3 x float4)/record.
// v5: "look like the 6.3 TB/s copy kernel".
//   - PLAIN stores (NT bit dropped: fill kernel proves plain-store path = 6.2 TB/s).
//   - ONE lgkm-only barrier per tile (raw s_barrier + s_waitcnt lgkmcnt(0)):
//     never drains vmcnt in the loop -> stores stay in flight across barriers (T4).
//     Safe: only cross-wave state is LDS (tab write-once; cls double-buffered,
//     write targets buf^1, barrier separates readers of buf from writers of buf).
//     Global stores are never read back; idx prefetch -> ds_write gets a
//     compiler-inserted vmcnt wait on its own data.
//   - idx prefetch for tile+1 issued BEFORE the gather/store phase (latency hides).
__device__ __forceinline__ void barrier_lgkm_only()
{
    asm volatile("s_waitcnt lgkmcnt(0)" ::: "memory");
    __builtin_amdgcn_s_barrier();
    asm volatile("" ::: "memory");
}

__device__ __forceinline__ i4 load_idx4(const int* __restrict__ rel_pos,
                                        unsigned int r, unsigned int n_rec)
{
    i4 rv;
    if (r + 3u < n_rec) {
        rv = *(const i4*)&rel_pos[r];          // coalesced dwordx4
    } else {
#pragma unroll
        for (int e = 0; e < 4; ++e)
            rv[e] = (r + (unsigned)e < n_rec) ? rel_pos[r + e] : 0;
    }
    return rv;
}

__global__ __launch_bounds__(BLOCK) void gather12_v5(
    const int* __restrict__ rel_pos,
    const float* __restrict__ W,        // [12][64] float32
    f4* __restrict__ out,
    unsigned int n_rec,
    unsigned int n_tiles)
{
    __shared__ float tab[64 * 12];      // tab[c*12+h] = W[h][c]; chunks 16B-aligned
    __shared__ int cls[2][TILE];        // double-buffered index tile

    const int t = threadIdx.x;

    // table: once per block (768 floats)
#pragma unroll
    for (int i = 0; i < 3; ++i) {
        int idx = t + i * BLOCK;        // 0..767
        tab[(idx & 63) * 12 + (idx >> 6)] = W[idx];
    }

    unsigned int tile = blockIdx.x;
    if (tile >= n_tiles) return;        // block-uniform

    // prologue: stage tile0 indices into cls[0]
    *(i4*)&cls[0][t * 4] = load_idx4(rel_pos, tile * TILE + (unsigned)t * 4u, n_rec);
    int cur = 0;

    const unsigned long long total_chunks = (unsigned long long)n_rec * 3ull;

    while (true) {
        const unsigned int next = tile + gridDim.x;
        const bool have_next = (next < n_tiles);        // block-uniform

        barrier_lgkm_only();            // cls[cur] (+tab on first pass) visible

        // prefetch next tile's indices into regs; no wait here
        i4 rv;
        if (have_next)
            rv = load_idx4(rel_pos, next * TILE + (unsigned)t * 4u, n_rec);

        // gather + coalesced store: 3072 chunks, 12 per thread
        const unsigned long long chunkBase = (unsigned long long)tile * (TILE * 3ull);
        if ((unsigned long long)(tile + 1u) * TILE <= (unsigned long long)n_rec) {
            // full tile fast path: no per-chunk guard, pure store stream
#pragma unroll
            for (int k = 0; k < 12; ++k) {
                unsigned int j = (unsigned int)t + BLOCK * (unsigned int)k;
                unsigned int p = j / 3u;                 // const divisor -> magic mul
                unsigned int s = j - p * 3u;             // 0,1,2
                unsigned int c = (unsigned int)cls[cur][p];   // LDS broadcast x3
                out[chunkBase + j] = *(const f4*)(tab + c * 12u + 4u * s);
            }
        } else {
#pragma unroll
            for (int k = 0; k < 12; ++k) {
                unsigned int j = (unsigned int)t + BLOCK * (unsigned int)k;
                unsigned long long g = chunkBase + j;
                if (g < total_chunks) {
                    unsigned int p = j / 3u;
                    unsigned int s = j - p * 3u;
                    unsigned int c = (unsigned int)cls[cur][p];
                    out[g] = *(const f4*)(tab + c * 12u + 4u * s);
                }
            }
        }

        if (!have_next) break;
        // stage next tile into the other buffer (vmcnt wait on rv auto-inserted)
        *(i4*)&cls[cur ^ 1][t * 4] = rv;
        cur ^= 1;
        tile = next;
    }
}

extern "C" void kernel_launch(void* const* d_in, const int* in_sizes, int n_in,
                              void* d_out, int out_size, void* d_ws, size_t ws_size,
                              hipStream_t stream)
{
    const int* rel_pos = (const int*)d_in[0];
    // d_in[1] = hidden_states: unused (reference only uses its dtype)
    const float* W = (const float*)d_in[2];

    const unsigned int n_rec = (unsigned int)in_sizes[0];          // 4*2048*2048
    const unsigned int n_tiles = (n_rec + TILE - 1) / TILE;        // 16384
    const unsigned int blocks = (n_tiles < NBLK) ? n_tiles : NBLK; // 2048

    gather12_v5<<<blocks, BLOCK, 0, stream>>>(rel_pos, W, (f4*)d_out, n_rec, n_tiles);
}